// Round 5
// baseline (112.318 us; speedup 1.0000x reference)
//
#include <hip/hip_runtime.h>

#define HH 4096
#define WW 4096

typedef float v4f __attribute__((ext_vector_type(4)));

__device__ __forceinline__ float fast_tanh(float x) {
    // tanh(x) = 1 - 2/(exp(2x)+1); saturates correctly for |x| large.
    float e = __expf(2.0f * x);
    return 1.0f - 2.0f * __builtin_amdgcn_rcpf(e + 1.0f);
}

__global__ __launch_bounds__(256) void bio_kernel(
    const float* __restrict__ v,
    const float* __restrict__ na,
    const float* __restrict__ kk,
    const float* __restrict__ ca,
    float* __restrict__ out)
{
    int tid = blockIdx.x * 256 + (int)threadIdx.x;   // 2M threads
    int r  = tid >> 9;         // row, 0..4095  (512 8-float groups per row)
    int c8 = tid & 511;
    int c  = c8 * 8;
    int base = r * WW + c;

    // reflect padding (mirror excluding edge)
    int rup = (r == 0)      ? 1      : r - 1;
    int rdn = (r == HH - 1) ? HH - 2 : r + 1;
    int bup = rup * WW + c;
    int bdn = rdn * WW + c;

    // voltage: cached loads (stencil halo is the only reused data)
    v4f vc0 = *(const v4f*)(v + base);
    v4f vc1 = *(const v4f*)(v + base + 4);
    v4f vu0 = *(const v4f*)(v + bup);
    v4f vu1 = *(const v4f*)(v + bup + 4);
    v4f vd0 = *(const v4f*)(v + bdn);
    v4f vd1 = *(const v4f*)(v + bdn + 4);

    // single-use streams: non-temporal, keep L2/L3 for voltage
    v4f na0 = __builtin_nontemporal_load((const v4f*)(na + base));
    v4f na1 = __builtin_nontemporal_load((const v4f*)(na + base + 4));
    v4f k0  = __builtin_nontemporal_load((const v4f*)(kk + base));
    v4f k1  = __builtin_nontemporal_load((const v4f*)(kk + base + 4));
    v4f ca0 = __builtin_nontemporal_load((const v4f*)(ca + base));
    v4f ca1 = __builtin_nontemporal_load((const v4f*)(ca + base + 4));

    // left/right horizontal neighbors via cross-lane shuffle:
    // a wave's 64 lanes cover 512 contiguous floats of ONE row (1024/row -> no straddle).
    float vl = __shfl_up(vc1.w, 1);    // lane i <- lane i-1's element 7
    float vr = __shfl_down(vc0.x, 1);  // lane i <- lane i+1's element 0
    int lane = (int)threadIdx.x & 63;
    if (lane == 0)  vl = (c == 0)       ? vc0.y : v[base - 1];   // reflect: col 1
    if (lane == 63) vr = (c + 8 == WW)  ? vc1.z : v[base + 8];   // reflect: col W-2

    float cv[8]  = {vc0.x, vc0.y, vc0.z, vc0.w, vc1.x, vc1.y, vc1.z, vc1.w};
    float uu[8]  = {vu0.x, vu0.y, vu0.z, vu0.w, vu1.x, vu1.y, vu1.z, vu1.w};
    float dd[8]  = {vd0.x, vd0.y, vd0.z, vd0.w, vd1.x, vd1.y, vd1.z, vd1.w};
    float lf[8]  = {vl,    vc0.x, vc0.y, vc0.z, vc0.w, vc1.x, vc1.y, vc1.z};
    float rt[8]  = {vc0.y, vc0.z, vc0.w, vc1.x, vc1.y, vc1.z, vc1.w, vr};
    float nai[8] = {na0.x, na0.y, na0.z, na0.w, na1.x, na1.y, na1.z, na1.w};
    float ki[8]  = {k0.x,  k0.y,  k0.z,  k0.w,  k1.x,  k1.y,  k1.z,  k1.w};
    float cai[8] = {ca0.x, ca0.y, ca0.z, ca0.w, ca1.x, ca1.y, ca1.z, ca1.w};

    float o0[8], o1[8], o2[8], o3[8];
#pragma unroll
    for (int i = 0; i < 8; ++i) {
        float lap  = uu[i] + dd[i] + lf[i] + rt[i] - 4.0f * cv[i];
        float vupd = 0.5f * lap + 0.1f * nai[i] - 0.05f * ki[i] + 0.08f * cai[i];
        float nv   = fast_tanh(cv[i] + 0.1f * vupd);
        o0[i] = nv;
        o1[i] = nai[i] * 0.95f + 0.05f * fmaxf(nv, 0.0f);
        o2[i] = ki[i]  * 0.95f + 0.05f * fmaxf(-nv, 0.0f);
        o3[i] = cai[i] * 0.95f + 0.05f * fabsf(nv);
    }

    const int HW = HH * WW;
    // streaming outputs: non-temporal, don't pollute L2/L3
    __builtin_nontemporal_store((v4f){o0[0],o0[1],o0[2],o0[3]}, (v4f*)(out + base));
    __builtin_nontemporal_store((v4f){o0[4],o0[5],o0[6],o0[7]}, (v4f*)(out + base + 4));
    __builtin_nontemporal_store((v4f){o1[0],o1[1],o1[2],o1[3]}, (v4f*)(out + HW + base));
    __builtin_nontemporal_store((v4f){o1[4],o1[5],o1[6],o1[7]}, (v4f*)(out + HW + base + 4));
    __builtin_nontemporal_store((v4f){o2[0],o2[1],o2[2],o2[3]}, (v4f*)(out + 2*HW + base));
    __builtin_nontemporal_store((v4f){o2[4],o2[5],o2[6],o2[7]}, (v4f*)(out + 2*HW + base + 4));
    __builtin_nontemporal_store((v4f){o3[0],o3[1],o3[2],o3[3]}, (v4f*)(out + 3*HW + base));
    __builtin_nontemporal_store((v4f){o3[4],o3[5],o3[6],o3[7]}, (v4f*)(out + 3*HW + base + 4));
}

extern "C" void kernel_launch(void* const* d_in, const int* in_sizes, int n_in,
                              void* d_out, int out_size, void* d_ws, size_t ws_size,
                              hipStream_t stream) {
    const float* v  = (const float*)d_in[0];
    const float* na = (const float*)d_in[1];
    const float* kk = (const float*)d_in[2];
    const float* ca = (const float*)d_in[3];
    float* out = (float*)d_out;

    int total = HH * (WW / 8);           // 2M threads, 8 cols each
    int block = 256;
    int grid  = (total + block - 1) / block;   // 8192
    bio_kernel<<<grid, block, 0, stream>>>(v, na, kk, ca, out);
}

// Round 6
// 90.012 us; speedup vs baseline: 1.2478x; 1.2478x over previous
//
#include <hip/hip_runtime.h>

#define HH 4096
#define WW 4096

typedef float v4f __attribute__((ext_vector_type(4)));

__device__ __forceinline__ float fast_tanh(float x) {
    // tanh(x) = 1 - 2/(exp(2x)+1); saturates correctly for |x| large.
    float e = __expf(2.0f * x);
    return 1.0f - 2.0f * __builtin_amdgcn_rcpf(e + 1.0f);
}

__global__ __launch_bounds__(256) void bio_kernel(
    const float* __restrict__ v,
    const float* __restrict__ na,
    const float* __restrict__ kk,
    const float* __restrict__ ca,
    float* __restrict__ out)
{
    // XCD-bijective swizzle: gridDim.x = 16384 (divisible by 8). Hardware
    // round-robins physical block id across 8 XCDs; remap so each XCD owns a
    // contiguous band of 2048 blocks (= 512 rows). Vertical stencil neighbors
    // (+-4 block ids) then stay in the SAME XCD's L2 instead of being served
    // cross-XCD via L3/fabric.
    int bid   = blockIdx.x;
    int chunk = gridDim.x >> 3;                 // 2048
    int lb    = (bid & 7) * chunk + (bid >> 3); // bijective since grid % 8 == 0
    int tid   = lb * 256 + (int)threadIdx.x;    // 4M threads

    int r  = tid >> 10;        // row, 0..4095  (1024 float4-quarters/row)
    int c4 = tid & 1023;
    int c  = c4 * 4;
    int base = r * WW + c;

    // reflect padding (mirror excluding edge)
    int rup = (r == 0)      ? 1      : r - 1;
    int rdn = (r == HH - 1) ? HH - 2 : r + 1;

    // voltage: cached loads (stencil halo is the only reused data)
    v4f vc = *(const v4f*)(v + base);
    v4f vu = *(const v4f*)(v + rup * WW + c);
    v4f vd = *(const v4f*)(v + rdn * WW + c);

    // single-use streams: non-temporal loads, keep L2/L3 for voltage
    v4f na4 = __builtin_nontemporal_load((const v4f*)(na + base));
    v4f k4  = __builtin_nontemporal_load((const v4f*)(kk + base));
    v4f ca4 = __builtin_nontemporal_load((const v4f*)(ca + base));

    // left/right neighbors via cross-lane shuffle instead of extra loads:
    // a wave's 64 lanes cover 256 contiguous floats of ONE row.
    float vl = __shfl_up(vc.w, 1);    // lane i <- lane i-1's last element
    float vr = __shfl_down(vc.x, 1);  // lane i <- lane i+1's first element
    int lane = (int)threadIdx.x & 63;
    if (lane == 0)  vl = (c == 0)      ? vc.y : v[base - 1];   // reflect: col 1
    if (lane == 63) vr = (c + 4 == WW) ? vc.z : v[base + 4];   // reflect: col W-2

    float cv[4]  = {vc.x, vc.y, vc.z, vc.w};
    float uu[4]  = {vu.x, vu.y, vu.z, vu.w};
    float dd[4]  = {vd.x, vd.y, vd.z, vd.w};
    float lf[4]  = {vl,   vc.x, vc.y, vc.z};
    float rt[4]  = {vc.y, vc.z, vc.w, vr};
    float nai[4] = {na4.x, na4.y, na4.z, na4.w};
    float ki[4]  = {k4.x,  k4.y,  k4.z,  k4.w};
    float cai[4] = {ca4.x, ca4.y, ca4.z, ca4.w};

    float o0[4], o1[4], o2[4], o3[4];
#pragma unroll
    for (int i = 0; i < 4; ++i) {
        float lap  = uu[i] + dd[i] + lf[i] + rt[i] - 4.0f * cv[i];
        float vupd = 0.5f * lap + 0.1f * nai[i] - 0.05f * ki[i] + 0.08f * cai[i];
        float nv   = fast_tanh(cv[i] + 0.1f * vupd);
        o0[i] = nv;
        o1[i] = nai[i] * 0.95f + 0.05f * fmaxf(nv, 0.0f);
        o2[i] = ki[i]  * 0.95f + 0.05f * fmaxf(-nv, 0.0f);
        o3[i] = cai[i] * 0.95f + 0.05f * fabsf(nv);
    }
    v4f ov  = (v4f){o0[0], o0[1], o0[2], o0[3]};
    v4f ona = (v4f){o1[0], o1[1], o1[2], o1[3]};
    v4f okk = (v4f){o2[0], o2[1], o2[2], o2[3]};
    v4f oca = (v4f){o3[0], o3[1], o3[2], o3[3]};

    const int HW = HH * WW;
    // streaming outputs: non-temporal, don't pollute L2/L3
    __builtin_nontemporal_store(ov,  (v4f*)(out + base));
    __builtin_nontemporal_store(ona, (v4f*)(out + HW + base));
    __builtin_nontemporal_store(okk, (v4f*)(out + 2 * HW + base));
    __builtin_nontemporal_store(oca, (v4f*)(out + 3 * HW + base));
}

extern "C" void kernel_launch(void* const* d_in, const int* in_sizes, int n_in,
                              void* d_out, int out_size, void* d_ws, size_t ws_size,
                              hipStream_t stream) {
    const float* v  = (const float*)d_in[0];
    const float* na = (const float*)d_in[1];
    const float* kk = (const float*)d_in[2];
    const float* ca = (const float*)d_in[3];
    float* out = (float*)d_out;

    int total = HH * (WW / 4);           // 4M threads, 4 cols each
    int block = 256;
    int grid  = (total + block - 1) / block;   // 16384, divisible by 8
    bio_kernel<<<grid, block, 0, stream>>>(v, na, kk, ca, out);
}